// Round 6
// baseline (1004.464 us; speedup 1.0000x reference)
//
#include <hip/hip_runtime.h>

#define H    64
#define TT   1024
#define MB   8      // batch rows per workgroup
#define NW   512    // 8 waves
#define NWG  256
#define GSP  584    // gate buffer row stride (floats); 584 % 32 == 8; 16B-aligned rows
#define HRUS 144    // h array row stride in ushorts (288 B = 72 dwords; 72 % 32 == 8)

typedef float f32x4 __attribute__((ext_vector_type(4)));
typedef int   i32x4 __attribute__((ext_vector_type(4)));

__device__ __forceinline__ unsigned short bf16_rne(float f) {
    unsigned u = __float_as_uint(f);
    u += 0x7FFFu + ((u >> 16) & 1u);
    return (unsigned short)(u >> 16);
}
__device__ __forceinline__ float fast_sigmoid(float x) {
    return __builtin_amdgcn_rcpf(1.0f + __expf(-x));
}
__device__ __forceinline__ float fast_tanh(float x) {
    float xx = fminf(fmaxf(x, -15.0f), 15.0f);
    float e  = __expf(2.0f * xx);
    return (e - 1.0f) * __builtin_amdgcn_rcpf(e + 1.0f);
}

// Same structure as R4/R5 (D = W·h^T, weights as AGPR-pinned A-operand via inline
// asm), with the MFMA hazard wait-states the compiler cannot insert around
// inline asm added INSIDE the asm blocks:
//   - "s_nop 1" before each tile's first MFMA:  v_accvgpr_write(d=0) -> MFMA SrcC read
//   - "s_nop 7; s_nop 7" after each tile's last MFMA: MFMA D-write -> v_accvgpr_read
// (MFMA->MFMA same-accumulator chains are HW-pipelined, no nops needed.)
// R5's failure (absmax 5e-2) is attributed to these missing wait states.
__global__ __launch_bounds__(NW, 2) void gru_mfma5(
    const float* __restrict__ x,
    const float* __restrict__ w_ih0, const float* __restrict__ w_hh0,
    const float* __restrict__ b_ih0, const float* __restrict__ b_hh0,
    const float* __restrict__ w_ih1, const float* __restrict__ w_hh1,
    const float* __restrict__ b_ih1, const float* __restrict__ b_hh1,
    const float* __restrict__ w_fc,  const float* __restrict__ b_fc,
    float* __restrict__ out)
{
    __shared__ __align__(16) float          xs[MB * TT];     // 32 KB
    __shared__ __align__(16) float          gA[MB * GSP];    // 18.25 KB
    __shared__ __align__(16) unsigned short hA[16 * HRUS];   // 4.5 KB

    const int tid  = threadIdx.x;
    const int wave = tid >> 6;
    const int lane = tid & 63;
    const int r    = lane & 15;        // A row within tile / D col (batch)
    const int q    = lane >> 4;        // k-group / D row-group
    const int b0g  = blockIdx.x * MB;

    for (int i = tid; i < 16*HRUS; i += NW) hA[i] = 0;
    for (int i = tid; i < MB*GSP;  i += NW) gA[i] = 0.0f;

    // stage x: wave w copies batch row b0g+w (coalesced float4)
    {
        const float* xrow = x + (size_t)(b0g + wave) * TT;
        float* xd = xs + wave * TT;
        #pragma unroll
        for (int u = 0; u < 4; ++u) {
            int idx = (u * 64 + lane) * 4;
            *(float4*)(xd + idx) = *(const float4*)(xrow + idx);
        }
    }

    // ---- persistent weight fragments (A operand), uniform 5 tiles/wave ----
    i32x4 whi[5][2], wlo[5][2];
    int   doff [5];
    bool  wr_ok[5];
    #pragma unroll
    for (int i = 0; i < 5; ++i) {
        const int n = 5 * wave + i;
        const float* W; int gr;
        if      (n < 12) { W = w_hh0; gr = 16 * n; }
        else if (n < 24) { W = w_ih1; gr = 16 * (n - 12); }
        else if (n < 36) { W = w_hh1; gr = 16 * (n - 24); }
        else             { W = w_hh0; gr = 0; }
        #pragma unroll
        for (int c = 0; c < 2; ++c) {
            // lane supplies A[row=r][k], k = 32c + 8q + j  (A row = gate row gr+r)
            const float* wp = W + (gr + r) * H + 32 * c + 8 * q;
            float4 p0 = *(const float4*)wp;
            float4 p1 = *(const float4*)(wp + 4);
            float f[8] = {p0.x,p0.y,p0.z,p0.w,p1.x,p1.y,p1.z,p1.w};
            i32x4 vh, vl;
            #pragma unroll
            for (int j2 = 0; j2 < 4; ++j2) {
                unsigned short h0_ = bf16_rne(f[2*j2]);
                unsigned short h1_ = bf16_rne(f[2*j2+1]);
                unsigned short l0_ = bf16_rne(f[2*j2]   - __uint_as_float((unsigned)h0_ << 16));
                unsigned short l1_ = bf16_rne(f[2*j2+1] - __uint_as_float((unsigned)h1_ << 16));
                vh[j2] = (int)((unsigned)h0_ | ((unsigned)h1_ << 16));
                vl[j2] = (int)((unsigned)l0_ | ((unsigned)l1_ << 16));
            }
            whi[i][c] = vh;
            wlo[i][c] = vl;
        }
        doff [i] = (r & 7) * GSP + 16 * n + 4 * q;
        wr_ok[i] = (n < 36) && ((n < 24) == (r < 8));
    }

    // ---- loop-invariant LDS pointers ----
    // B-frag (h) reads: lane supplies B[k][col=r] = h[r][k], k = 32c+8q+j
    const unsigned short* hp0 = hA + r * HRUS + 8 * q;        // c=0 hi
    const unsigned short* hp1 = hA + r * HRUS + 8 * (4 + q);  // c=1 hi
    const unsigned short* hp2 = hp0 + 64;                     // c=0 lo
    const unsigned short* hp3 = hp1 + 64;                     // c=1 lo

    unsigned short* p0h = hA + wave * HRUS + lane;            // h0 hi
    unsigned short* p0l = p0h + 64;                           // h0 lo
    unsigned short* p1h = hA + (wave + 8) * HRUS + lane;      // h1 hi
    unsigned short* p1l = p1h + 64;                           // h1 lo

    const float* gp  = gA + wave * GSP;
    const float* xmy = xs + wave * TT;

    // ---- gate constants (wave = batch, lane = hidden j) ----
    const float wi0r = w_ih0[lane], wi0z = w_ih0[64+lane], wi0n = w_ih0[128+lane];
    const float c0r  = b_ih0[lane]     + b_hh0[lane];
    const float c0z  = b_ih0[64+lane]  + b_hh0[64+lane];
    const float bi0n = b_ih0[128+lane], bh0n = b_hh0[128+lane];
    const float c1r  = b_ih1[lane]     + b_hh1[lane];
    const float c1z  = b_ih1[64+lane]  + b_hh1[64+lane];
    const float bi1n = b_ih1[128+lane], bh1n = b_hh1[128+lane];
    const float wfc  = w_fc[lane];

    float h0reg = 0.0f, h1reg = 0.0f;
    __syncthreads();

    #pragma unroll 1
    for (int t = 0; t < TT; ++t) {
        // ---------------- G phase ----------------
        if (t > 0) {            // layer 1, step t-1
            float xr = gp[192+lane], xz = gp[256+lane], xn = gp[320+lane];
            float hr = gp[384+lane], hz = gp[448+lane], hn = gp[512+lane];
            float rr = fast_sigmoid(xr + hr + c1r);
            float zz = fast_sigmoid(xz + hz + c1z);
            float nn = fast_tanh(xn + bi1n + rr * (hn + bh1n));
            h1reg = fmaf(zz, h1reg - nn, nn);
            unsigned short hh = bf16_rne(h1reg);
            *p1h = hh;
            *p1l = bf16_rne(h1reg - __uint_as_float((unsigned)hh << 16));
        }
        {                        // layer 0, step t
            float xv  = xmy[t];
            float g0r = gp[lane], g0z = gp[64+lane], g0n = gp[128+lane];
            float rr = fast_sigmoid(fmaf(xv, wi0r, c0r) + g0r);
            float zz = fast_sigmoid(fmaf(xv, wi0z, c0z) + g0z);
            float nn = fast_tanh(fmaf(xv, wi0n, bi0n) + rr * (g0n + bh0n));
            h0reg = fmaf(zz, h0reg - nn, nn);
            unsigned short hh = bf16_rne(h0reg);
            *p0h = hh;
            *p0l = bf16_rne(h0reg - __uint_as_float((unsigned)hh << 16));
        }
        __syncthreads();

        // ---------------- M phase ----------------
        {
            const i32x4 hhi0 = *(const i32x4*)hp0;
            const i32x4 hhi1 = *(const i32x4*)hp1;
            const i32x4 hlo0 = *(const i32x4*)hp2;
            const i32x4 hlo1 = *(const i32x4*)hp3;
            #pragma unroll
            for (int i = 0; i < 5; ++i) {
                f32x4 d = {0.0f, 0.0f, 0.0f, 0.0f};
                // s_nop 1: cover v_accvgpr_write(d=0) -> MFMA SrcC-read hazard
                asm("s_nop 1\n\t"
                    "v_mfma_f32_16x16x32_bf16 %0, %1, %2, %0"
                    : "+a"(d) : "a"(whi[i][0]), "v"(hhi0));
                asm("v_mfma_f32_16x16x32_bf16 %0, %1, %2, %0"
                    : "+a"(d) : "a"(whi[i][1]), "v"(hhi1));
                asm("v_mfma_f32_16x16x32_bf16 %0, %1, %2, %0"
                    : "+a"(d) : "a"(whi[i][0]), "v"(hlo0));
                asm("v_mfma_f32_16x16x32_bf16 %0, %1, %2, %0"
                    : "+a"(d) : "a"(whi[i][1]), "v"(hlo1));
                asm("v_mfma_f32_16x16x32_bf16 %0, %1, %2, %0"
                    : "+a"(d) : "a"(wlo[i][0]), "v"(hhi0));
                // trailing nops: cover MFMA D-write -> v_accvgpr_read (store) hazard
                asm("v_mfma_f32_16x16x32_bf16 %0, %1, %2, %0\n\t"
                    "s_nop 7\n\t"
                    "s_nop 7"
                    : "+a"(d) : "a"(wlo[i][1]), "v"(hhi1));
                if (wr_ok[i]) {
                    *(f32x4*)(gA + doff[i]) = d;   // 4 consecutive gate cols, one b128
                }
            }
        }
        __syncthreads();
    }

    // final layer-1 gate (step TT-1)
    {
        float xr = gp[192+lane], xz = gp[256+lane], xn = gp[320+lane];
        float hr = gp[384+lane], hz = gp[448+lane], hn = gp[512+lane];
        float rr = fast_sigmoid(xr + hr + c1r);
        float zz = fast_sigmoid(xz + hz + c1z);
        float nn = fast_tanh(xn + bi1n + rr * (hn + bh1n));
        h1reg = fmaf(zz, h1reg - nn, nn);
    }
    // FC: out[b] = dot(h1, w_fc) + b_fc
    {
        float v = h1reg * wfc;
        #pragma unroll
        for (int s = 32; s > 0; s >>= 1) v += __shfl_xor(v, s, 64);
        if (lane == 0) out[b0g + wave] = v + b_fc[0];
    }
}

extern "C" void kernel_launch(void* const* d_in, const int* in_sizes, int n_in,
                              void* d_out, int out_size, void* d_ws, size_t ws_size,
                              hipStream_t stream) {
    (void)in_sizes; (void)n_in; (void)out_size; (void)d_ws; (void)ws_size;
    gru_mfma5<<<NWG, NW, 0, stream>>>(
        (const float*)d_in[0],
        (const float*)d_in[1], (const float*)d_in[2],
        (const float*)d_in[3], (const float*)d_in[4],
        (const float*)d_in[5], (const float*)d_in[6],
        (const float*)d_in[7], (const float*)d_in[8],
        (const float*)d_in[9], (const float*)d_in[10],
        (float*)d_out);
}